// Round 8
// baseline (141.587 us; speedup 1.0000x reference)
//
#include <hip/hip_runtime.h>
#include <hip/hip_bf16.h>
#include <cstdint>

// Problem constants
#define NWORDS 16384   // B*S
#define NCH    20      // chars per word
#define CEDIM  32      // char emb dim
#define WEDIM  512     // output channels

typedef __attribute__((ext_vector_type(8)))  short bf16x8;
typedef __attribute__((ext_vector_type(16))) float f32x16;

__device__ __forceinline__ unsigned short f2bf(float f){
    union { float f; unsigned int u; } v; v.f = f;
    unsigned int u = v.u + 0x7fffu + ((v.u >> 16) & 1u);
    return (unsigned short)(u >> 16);
}

// Prep v3:
//  wbf3 layout for 32x32x16 B-frags, perfectly coalesced per-wave loads:
//    idx = (((cc*8 + s)*2 + lh)*32 + col)*8 + j   (cc=colchunk32 0..15)
//    value = bf16( W[o = cc*32+col][kk' = s*16 + lh*8 + j] ), kk' = k*32 + i
//          = bf16( cnn[o*132 + i*4 + k] ),  i = kk'&31, k = kk'>>5
//  cembbf: [256][32] bf16 (no zero row needed -- no padding tiles anymore)
//  bias[o] = sum_k cnn[o][32][k]  (lang-bit row folded to bias)
__global__ __launch_bounds__(256) void prep_kernel(const float* __restrict__ cnn,
                                                   const float* __restrict__ cemb,
                                                   unsigned short* __restrict__ wbf3,
                                                   unsigned short* __restrict__ cembbf,
                                                   float* __restrict__ bias){
    int idx = blockIdx.x * 256 + threadIdx.x;
    if (idx < 65536){
        int j   = idx & 7;
        int col = (idx >> 3) & 31;
        int lh  = (idx >> 8) & 1;
        int s   = (idx >> 9) & 7;
        int cc  = idx >> 12;
        int o   = cc*32 + col;
        int kk  = s*16 + lh*8 + j;
        int i   = kk & 31, k = kk >> 5;
        wbf3[idx] = f2bf(cnn[o*132 + i*4 + k]);
    } else if (idx < 65536 + 256*CEDIM){
        int r = idx - 65536;
        cembbf[r] = f2bf(cemb[r]);
    } else if (idx < 65536 + 256*CEDIM + WEDIM){
        int o = idx - (65536 + 256*CEDIM);
        const float* p = cnn + o*132 + 128;
        bias[o] = p[0] + p[1] + p[2] + p[3];
    }
}

// Round 8: t-major 32x32x16 tiles. Rows = 32 words, cols = 32 channels,
// one fresh accumulator per t (t = 0..16), max folded in registers --
// no t16 waste tile, no shuffles, no LDS, no barriers. B-frags loaded once
// per chunk (reused 17x); A-frags slide a 4-char window (2 new 16B L1
// gathers per t). Block = 128 threads (2 waves); wave = 32 words x 64 cols.
__global__ __attribute__((amdgpu_waves_per_eu(3))) __launch_bounds__(128)
void conv_kernel(
    const int* __restrict__ data,              // [16384]
    const int* __restrict__ spelling,          // [50000][20]
    const unsigned short* __restrict__ cembbf, // [256][32] bf16
    const unsigned short* __restrict__ wbf3,   // [16][8][2][32][8] bf16
    const float* __restrict__ bias,            // [512]
    float* __restrict__ out)                   // [16384][512] f32
{
    const int tid  = threadIdx.x;
    const int wv   = tid >> 6;        // wave 0..1
    const int lane = tid & 63;
    const int ln31 = lane & 31;       // A: word row; C/D: col offset
    const int lh   = lane >> 5;
    const int wgrp = blockIdx.x >> 2; // 512 word groups of 32
    const int cg   = blockIdx.x & 3;  // 4 col groups of 128
    const int wbase = wgrp * 32;

    // ---- char ids for this lane's word (A rows): 5 x int4, packed to bytes ----
    int wd = data[wbase + ln31];
    const int4* sp = reinterpret_cast<const int4*>(spelling + wd*NCH);
    int4 s0 = sp[0], s1 = sp[1], s2 = sp[2], s3 = sp[3], s4 = sp[4];
    unsigned idpk[5];
    idpk[0] = (unsigned)s0.x | ((unsigned)s0.y<<8) | ((unsigned)s0.z<<16) | ((unsigned)s0.w<<24);
    idpk[1] = (unsigned)s1.x | ((unsigned)s1.y<<8) | ((unsigned)s1.z<<16) | ((unsigned)s1.w<<24);
    idpk[2] = (unsigned)s2.x | ((unsigned)s2.y<<8) | ((unsigned)s2.z<<16) | ((unsigned)s2.w<<24);
    idpk[3] = (unsigned)s3.x | ((unsigned)s3.y<<8) | ((unsigned)s3.z<<16) | ((unsigned)s3.w<<24);
    idpk[4] = (unsigned)s4.x | ((unsigned)s4.y<<8) | ((unsigned)s4.z<<16) | ((unsigned)s4.w<<24);

    const char* cb = (const char*)cembbf;
    const char* wb = (const char*)wbf3;

    // A-frag(c, p): lane holds A[m=ln31][kk' = s*16 + lh*8 + j] for step s,
    // c = t + (s>>1), p = s&1: 16B at cembbf[id(c)]*64 + p*32 + lh*16
    auto afrag = [&](int c, int p) -> bf16x8 {
        unsigned id = (idpk[c >> 2] >> ((c & 3)*8)) & 0xFFu;
        return *reinterpret_cast<const bf16x8*>(cb + id*64 + p*32 + lh*16);
    };

    f32x16 zz;
    #pragma unroll
    for (int r = 0; r < 16; ++r) zz[r] = 0.f;

    #pragma unroll 1
    for (int ch2 = 0; ch2 < 2; ++ch2){
        const int cc16 = cg*4 + wv*2 + ch2;   // 32-col chunk index 0..15
        const int colb = cc16*32;

        // B-frags for all 8 K-steps: 1 KB fully-coalesced load each, reused 17x
        const char* wbb = wb + cc16*8192 + lane*16;
        bf16x8 bs[8];
        #pragma unroll
        for (int s = 0; s < 8; ++s)
            bs[s] = *reinterpret_cast<const bf16x8*>(wbb + s*1024);

        // A window: chars t..t+3, two i-halves each
        bf16x8 aw[4][2];
        #pragma unroll
        for (int c = 0; c < 4; ++c){
            aw[c][0] = afrag(c, 0);
            aw[c][1] = afrag(c, 1);
        }

        f32x16 vmax;
        #pragma unroll
        for (int t = 0; t < 17; ++t){
            f32x16 acc;
            acc = __builtin_amdgcn_mfma_f32_32x32x16_bf16(aw[ t   &3][0], bs[0], zz,  0,0,0);
            acc = __builtin_amdgcn_mfma_f32_32x32x16_bf16(aw[ t   &3][1], bs[1], acc, 0,0,0);
            acc = __builtin_amdgcn_mfma_f32_32x32x16_bf16(aw[(t+1)&3][0], bs[2], acc, 0,0,0);
            acc = __builtin_amdgcn_mfma_f32_32x32x16_bf16(aw[(t+1)&3][1], bs[3], acc, 0,0,0);
            acc = __builtin_amdgcn_mfma_f32_32x32x16_bf16(aw[(t+2)&3][0], bs[4], acc, 0,0,0);
            acc = __builtin_amdgcn_mfma_f32_32x32x16_bf16(aw[(t+2)&3][1], bs[5], acc, 0,0,0);
            acc = __builtin_amdgcn_mfma_f32_32x32x16_bf16(aw[(t+3)&3][0], bs[6], acc, 0,0,0);
            acc = __builtin_amdgcn_mfma_f32_32x32x16_bf16(aw[(t+3)&3][1], bs[7], acc, 0,0,0);

            if (t == 0){
                vmax = acc;
            } else {
                #pragma unroll
                for (int r = 0; r < 16; ++r) vmax[r] = fmaxf(vmax[r], acc[r]);
            }
            if (t < 16){
                // slide: char t+4 replaces char t in slot (t&3)
                aw[t&3][0] = afrag(t+4, 0);
                aw[t&3][1] = afrag(t+4, 1);
            }
        }

        // ---- epilogue: direct stores, no shuffles ----
        // C/D: col = colb + ln31, row(word) = (r&3) + 8*(r>>2) + 4*lh
        float bv = bias[colb + ln31];
        #pragma unroll
        for (int r = 0; r < 16; ++r){
            int row = (r & 3) + 8*(r >> 2) + 4*lh;
            __builtin_nontemporal_store(vmax[r] + bv,
                out + (wbase + row)*WEDIM + colb + ln31);
        }
    }
}

extern "C" void kernel_launch(void* const* d_in, const int* in_sizes, int n_in,
                              void* d_out, int out_size, void* d_ws, size_t ws_size,
                              hipStream_t stream) {
    const float* cemb     = (const float*)d_in[0];   // char_emb_w [256*32]
    const float* cnn      = (const float*)d_in[1];   // cnn_w [512*33*4]
    const int*   data     = (const int*)d_in[2];     // [16384]
    const int*   spelling = (const int*)d_in[3];     // [50000*20]
    float* outp = (float*)d_out;

    unsigned short* wbf3   = (unsigned short*)d_ws;                       // 131072 B
    float*          bias   = (float*)((char*)d_ws + 131072);              // 2048 B
    unsigned short* cembbf = (unsigned short*)((char*)d_ws + 133120);     // 16384 B

    int prep_items = 65536 + 256*CEDIM + WEDIM;   // 74240
    prep_kernel<<<dim3((prep_items + 255)/256), dim3(256), 0, stream>>>(cnn, cemb, wbf3, cembbf, bias);
    conv_kernel<<<dim3(2048), dim3(128), 0, stream>>>(data, spelling, cembbf, wbf3, bias, outp);
}

// Round 9
// 104.752 us; speedup vs baseline: 1.3516x; 1.3516x over previous
//
#include <hip/hip_runtime.h>
#include <hip/hip_bf16.h>
#include <cstdint>

// Problem constants
#define NWORDS 16384   // B*S
#define NCH    20      // chars per word
#define CEDIM  32      // char emb dim
#define WEDIM  512     // output channels

typedef __attribute__((ext_vector_type(8)))  short bf16x8;
typedef __attribute__((ext_vector_type(16))) float f32x16;

__device__ __forceinline__ unsigned short f2bf(float f){
    union { float f; unsigned int u; } v; v.f = f;
    unsigned int u = v.u + 0x7fffu + ((v.u >> 16) & 1u);
    return (unsigned short)(u >> 16);
}

// Prep v3 (verified round 8):
//  wbf3 layout for 32x32x16 B-frags, coalesced 1 KB per-wave loads:
//    idx = (((cc*8 + s)*2 + lh)*32 + col)*8 + j   (cc = 32-col chunk 0..15)
//    value = bf16( W[o = cc*32+col][kk' = s*16 + lh*8 + j] ), kk' = k*32 + i
//  cembbf: [256][32] bf16; bias[o] = sum_k cnn[o][32][k] (lang-bit row)
__global__ __launch_bounds__(256) void prep_kernel(const float* __restrict__ cnn,
                                                   const float* __restrict__ cemb,
                                                   unsigned short* __restrict__ wbf3,
                                                   unsigned short* __restrict__ cembbf,
                                                   float* __restrict__ bias){
    int idx = blockIdx.x * 256 + threadIdx.x;
    if (idx < 65536){
        int j   = idx & 7;
        int col = (idx >> 3) & 31;
        int lh  = (idx >> 8) & 1;
        int s   = (idx >> 9) & 7;
        int cc  = idx >> 12;
        int o   = cc*32 + col;
        int kk  = s*16 + lh*8 + j;
        int i   = kk & 31, k = kk >> 5;
        wbf3[idx] = f2bf(cnn[o*132 + i*4 + k]);
    } else if (idx < 65536 + 256*CEDIM){
        int r = idx - 65536;
        cembbf[r] = f2bf(cemb[r]);
    } else if (idx < 65536 + 256*CEDIM + WEDIM){
        int o = idx - (65536 + 256*CEDIM);
        const float* p = cnn + o*132 + 128;
        bias[o] = p[0] + p[1] + p[2] + p[3];
    }
}

// Round 9 = round 8 structure (t-major 32x32x16, no LDS/barriers/shuffles,
// zero waste MFMAs) with waves_per_eu(2): the 256-reg budget. Rounds 4 and 8
// both proved waves_per_eu>=3 makes the allocator spill (~100 MB scratch
// round-trips); (2,*) has never spilled. Live set ~150 regs fits w/ headroom.
__global__ __attribute__((amdgpu_waves_per_eu(2))) __launch_bounds__(128)
void conv_kernel(
    const int* __restrict__ data,              // [16384]
    const int* __restrict__ spelling,          // [50000][20]
    const unsigned short* __restrict__ cembbf, // [256][32] bf16
    const unsigned short* __restrict__ wbf3,   // [16][8][2][32][8] bf16
    const float* __restrict__ bias,            // [512]
    float* __restrict__ out)                   // [16384][512] f32
{
    const int tid  = threadIdx.x;
    const int wv   = tid >> 6;        // wave 0..1
    const int lane = tid & 63;
    const int ln31 = lane & 31;       // A: word row; C/D: col offset
    const int lh   = lane >> 5;
    const int wgrp = blockIdx.x >> 2; // 512 word groups of 32
    const int cg   = blockIdx.x & 3;  // 4 col groups of 128
    const int wbase = wgrp * 32;

    // ---- char ids for this lane's word (A rows): 5 x int4, packed to bytes ----
    int wd = data[wbase + ln31];
    const int4* sp = reinterpret_cast<const int4*>(spelling + wd*NCH);
    int4 s0 = sp[0], s1 = sp[1], s2 = sp[2], s3 = sp[3], s4 = sp[4];
    unsigned idpk[5];
    idpk[0] = (unsigned)s0.x | ((unsigned)s0.y<<8) | ((unsigned)s0.z<<16) | ((unsigned)s0.w<<24);
    idpk[1] = (unsigned)s1.x | ((unsigned)s1.y<<8) | ((unsigned)s1.z<<16) | ((unsigned)s1.w<<24);
    idpk[2] = (unsigned)s2.x | ((unsigned)s2.y<<8) | ((unsigned)s2.z<<16) | ((unsigned)s2.w<<24);
    idpk[3] = (unsigned)s3.x | ((unsigned)s3.y<<8) | ((unsigned)s3.z<<16) | ((unsigned)s3.w<<24);
    idpk[4] = (unsigned)s4.x | ((unsigned)s4.y<<8) | ((unsigned)s4.z<<16) | ((unsigned)s4.w<<24);

    const char* cb = (const char*)cembbf;
    const char* wb = (const char*)wbf3;

    // A-frag(c, p): lane holds A[m=ln31][kk' = s*16 + lh*8 + j] for step s,
    // c = char index, p = s&1: 16B at cembbf[id(c)]*64 + p*32 + lh*16
    auto afrag = [&](int c, int p) -> bf16x8 {
        unsigned id = (idpk[c >> 2] >> ((c & 3)*8)) & 0xFFu;
        return *reinterpret_cast<const bf16x8*>(cb + id*64 + p*32 + lh*16);
    };

    f32x16 zz;
    #pragma unroll
    for (int r = 0; r < 16; ++r) zz[r] = 0.f;

    #pragma unroll 1
    for (int ch2 = 0; ch2 < 2; ++ch2){
        const int cc16 = cg*4 + wv*2 + ch2;   // 32-col chunk index 0..15
        const int colb = cc16*32;

        // B-frags for all 8 K-steps: 1 KB coalesced load each, reused 17x
        const char* wbb = wb + cc16*8192 + lane*16;
        bf16x8 bs[8];
        #pragma unroll
        for (int s = 0; s < 8; ++s)
            bs[s] = *reinterpret_cast<const bf16x8*>(wbb + s*1024);

        // A window: chars t..t+3, two i-halves each
        bf16x8 aw[4][2];
        #pragma unroll
        for (int c = 0; c < 4; ++c){
            aw[c][0] = afrag(c, 0);
            aw[c][1] = afrag(c, 1);
        }

        f32x16 vmax;
        #pragma unroll
        for (int t = 0; t < 17; ++t){
            f32x16 acc;
            acc = __builtin_amdgcn_mfma_f32_32x32x16_bf16(aw[ t   &3][0], bs[0], zz,  0,0,0);
            acc = __builtin_amdgcn_mfma_f32_32x32x16_bf16(aw[ t   &3][1], bs[1], acc, 0,0,0);
            acc = __builtin_amdgcn_mfma_f32_32x32x16_bf16(aw[(t+1)&3][0], bs[2], acc, 0,0,0);
            acc = __builtin_amdgcn_mfma_f32_32x32x16_bf16(aw[(t+1)&3][1], bs[3], acc, 0,0,0);
            acc = __builtin_amdgcn_mfma_f32_32x32x16_bf16(aw[(t+2)&3][0], bs[4], acc, 0,0,0);
            acc = __builtin_amdgcn_mfma_f32_32x32x16_bf16(aw[(t+2)&3][1], bs[5], acc, 0,0,0);
            acc = __builtin_amdgcn_mfma_f32_32x32x16_bf16(aw[(t+3)&3][0], bs[6], acc, 0,0,0);
            acc = __builtin_amdgcn_mfma_f32_32x32x16_bf16(aw[(t+3)&3][1], bs[7], acc, 0,0,0);

            if (t == 0){
                vmax = acc;
            } else {
                #pragma unroll
                for (int r = 0; r < 16; ++r) vmax[r] = fmaxf(vmax[r], acc[r]);
            }
            if (t < 16){
                // slide: char t+4 replaces char t in slot (t&3)
                aw[t&3][0] = afrag(t+4, 0);
                aw[t&3][1] = afrag(t+4, 1);
            }
        }

        // ---- epilogue: direct stores, no shuffles ----
        // C/D: col = colb + ln31, row(word) = (r&3) + 8*(r>>2) + 4*lh
        float bv = bias[colb + ln31];
        #pragma unroll
        for (int r = 0; r < 16; ++r){
            int row = (r & 3) + 8*(r >> 2) + 4*lh;
            __builtin_nontemporal_store(vmax[r] + bv,
                out + (wbase + row)*WEDIM + colb + ln31);
        }
    }
}

extern "C" void kernel_launch(void* const* d_in, const int* in_sizes, int n_in,
                              void* d_out, int out_size, void* d_ws, size_t ws_size,
                              hipStream_t stream) {
    const float* cemb     = (const float*)d_in[0];   // char_emb_w [256*32]
    const float* cnn      = (const float*)d_in[1];   // cnn_w [512*33*4]
    const int*   data     = (const int*)d_in[2];     // [16384]
    const int*   spelling = (const int*)d_in[3];     // [50000*20]
    float* outp = (float*)d_out;

    unsigned short* wbf3   = (unsigned short*)d_ws;                       // 131072 B
    float*          bias   = (float*)((char*)d_ws + 131072);              // 2048 B
    unsigned short* cembbf = (unsigned short*)((char*)d_ws + 133120);     // 16384 B

    int prep_items = 65536 + 256*CEDIM + WEDIM;   // 74240
    prep_kernel<<<dim3((prep_items + 255)/256), dim3(256), 0, stream>>>(cnn, cemb, wbf3, cembbf, bias);
    conv_kernel<<<dim3(2048), dim3(128), 0, stream>>>(data, spelling, cembbf, wbf3, bias, outp);
}

// Round 10
// 100.350 us; speedup vs baseline: 1.4109x; 1.0439x over previous
//
#include <hip/hip_runtime.h>
#include <hip/hip_bf16.h>
#include <cstdint>

// Problem constants
#define NWORDS 16384   // B*S
#define NCH    20      // chars per word
#define CEDIM  32      // char emb dim
#define WEDIM  512     // output channels
#define WPB    32      // words per block
#define NBLK   (NWORDS/WPB)   // 512

typedef __attribute__((ext_vector_type(8)))  short bf16x8;
typedef __attribute__((ext_vector_type(16))) float f32x16;

__device__ __forceinline__ unsigned short f2bf(float f){
    union { float f; unsigned int u; } v; v.f = f;
    unsigned int u = v.u + 0x7fffu + ((v.u >> 16) & 1u);
    return (unsigned short)(u >> 16);
}

// Prep v3 (verified rounds 8-9):
//  wbf3: B-frag layout for 32x32x16, coalesced 1 KB per-wave loads:
//    idx = (((cc*8 + s)*2 + lh)*32 + col)*8 + j   (cc = 32-col chunk 0..15)
//    value = bf16( W[o = cc*32+col][kk' = s*16 + lh*8 + j] ), kk' = k*32 + i
//  cembbf: [256][32] bf16; bias[o] = sum_k cnn[o][32][k] (lang-bit row)
__global__ __launch_bounds__(256) void prep_kernel(const float* __restrict__ cnn,
                                                   const float* __restrict__ cemb,
                                                   unsigned short* __restrict__ wbf3,
                                                   unsigned short* __restrict__ cembbf,
                                                   float* __restrict__ bias){
    int idx = blockIdx.x * 256 + threadIdx.x;
    if (idx < 65536){
        int j   = idx & 7;
        int col = (idx >> 3) & 31;
        int lh  = (idx >> 8) & 1;
        int s   = (idx >> 9) & 7;
        int cc  = idx >> 12;
        int o   = cc*32 + col;
        int kk  = s*16 + lh*8 + j;
        int i   = kk & 31, k = kk >> 5;
        wbf3[idx] = f2bf(cnn[o*132 + i*4 + k]);
    } else if (idx < 65536 + 256*CEDIM){
        int r = idx - 65536;
        cembbf[r] = f2bf(cemb[r]);
    } else if (idx < 65536 + 256*CEDIM + WEDIM){
        int o = idx - (65536 + 256*CEDIM);
        const float* p = cnn + o*132 + 128;
        bias[o] = p[0] + p[1] + p[2] + p[3];
    }
}

// Round 10: t-major 32x32x16 (verified R8/R9) + LDS A-fragment cache.
// One 512-thread block = 32 words x all 512 cols. Staging gathers each
// word's 20 emb rows ONCE (vs 8x replicated per-wave gathers in R9 --
// the scattered-gather TA pipe was ~30 us/CU, the real R9 limiter) and
// stores them transposed in the exact A-frag layout, so compute-loop
// A-access is a conflict-free stride-16 ds_read_b128. One barrier total.
// waves_per_eu(2): the only never-spilled setting (R4/R8 spilled at >=3).
__global__ __attribute__((amdgpu_waves_per_eu(2))) __launch_bounds__(512)
void conv_kernel(
    const int* __restrict__ data,              // [16384]
    const int* __restrict__ spelling,          // [50000][20]
    const unsigned short* __restrict__ cembbf, // [256][32] bf16
    const unsigned short* __restrict__ wbf3,   // [16][8][2][32][8] bf16
    const float* __restrict__ bias,            // [512]
    float* __restrict__ out)                   // [16384][512] f32
{
    // sA[c][q=p*2+lh][word] : 16B frag = cembbf[id(word,c)][ bytes q*16.. ]
    __shared__ __align__(16) char sA[20*4*32*16];   // 40960 B

    const int tid  = threadIdx.x;
    const int wv   = tid >> 6;        // wave 0..7
    const int lane = tid & 63;
    const int ln31 = lane & 31;       // A row (word) / C-D col offset
    const int lh   = lane >> 5;
    const int wbase = blockIdx.x * WPB;

    // ---- staging: 640 tasks (c,w), each copies one 64 B emb row ----
    {
        auto stage = [&](int c, int w){
            int wd = data[wbase + w];                       // 32 dwords, L1
            int id = spelling[wd*NCH + c];                  // scattered dword
            const uint4* src = reinterpret_cast<const uint4*>(cembbf + id*CEDIM);
            #pragma unroll
            for (int q = 0; q < 4; ++q){
                uint4 v = src[q];
                *reinterpret_cast<uint4*>(sA + ((c*4 + q) << 9) + (w << 4)) = v;
            }
        };
        stage(tid >> 5, tid & 31);                 // c = 0..15
        if (tid < 128) stage(16 + (tid >> 5), tid & 31);   // c = 16..19
    }
    __syncthreads();

    const char* wb = (const char*)wbf3;

    // A-frag via LDS: lane holds A[m=ln31][kk'=s*16+lh*8+j], char c, half p=s&1
    auto ldA = [&](int c, int p) -> bf16x8 {
        return *reinterpret_cast<const bf16x8*>(
            sA + ((c*4 + p*2 + lh) << 9) + (ln31 << 4));
    };

    f32x16 zz;
    #pragma unroll
    for (int r = 0; r < 16; ++r) zz[r] = 0.f;

    #pragma unroll 1
    for (int half = 0; half < 2; ++half){
        const int cc16 = wv + half*8;     // 32-col chunk 0..15
        const int colb = cc16*32;

        // B-frags for all 8 K-steps: 1 KB coalesced loads, reused 17x (L2-hot)
        const char* wbb = wb + cc16*8192 + lane*16;
        bf16x8 bs[8];
        #pragma unroll
        for (int s = 0; s < 8; ++s)
            bs[s] = *reinterpret_cast<const bf16x8*>(wbb + s*1024);

        // sliding A window: chars t..t+3, two i-halves each
        bf16x8 aw[4][2];
        #pragma unroll
        for (int c = 0; c < 4; ++c){
            aw[c][0] = ldA(c, 0);
            aw[c][1] = ldA(c, 1);
        }

        f32x16 vmax;
        #pragma unroll
        for (int t = 0; t < 17; ++t){
            f32x16 acc;
            acc = __builtin_amdgcn_mfma_f32_32x32x16_bf16(aw[ t   &3][0], bs[0], zz,  0,0,0);
            acc = __builtin_amdgcn_mfma_f32_32x32x16_bf16(aw[ t   &3][1], bs[1], acc, 0,0,0);
            acc = __builtin_amdgcn_mfma_f32_32x32x16_bf16(aw[(t+1)&3][0], bs[2], acc, 0,0,0);
            acc = __builtin_amdgcn_mfma_f32_32x32x16_bf16(aw[(t+1)&3][1], bs[3], acc, 0,0,0);
            acc = __builtin_amdgcn_mfma_f32_32x32x16_bf16(aw[(t+2)&3][0], bs[4], acc, 0,0,0);
            acc = __builtin_amdgcn_mfma_f32_32x32x16_bf16(aw[(t+2)&3][1], bs[5], acc, 0,0,0);
            acc = __builtin_amdgcn_mfma_f32_32x32x16_bf16(aw[(t+3)&3][0], bs[6], acc, 0,0,0);
            acc = __builtin_amdgcn_mfma_f32_32x32x16_bf16(aw[(t+3)&3][1], bs[7], acc, 0,0,0);

            if (t == 0){
                vmax = acc;
            } else {
                #pragma unroll
                for (int r = 0; r < 16; ++r) vmax[r] = fmaxf(vmax[r], acc[r]);
            }
            if (t < 16){
                aw[t&3][0] = ldA(t+4, 0);
                aw[t&3][1] = ldA(t+4, 1);
            }
        }

        // ---- epilogue: direct stores, no shuffles ----
        // C/D: col = colb + ln31, row(word) = (r&3) + 8*(r>>2) + 4*lh
        float bv = bias[colb + ln31];
        #pragma unroll
        for (int r = 0; r < 16; ++r){
            int row = (r & 3) + 8*(r >> 2) + 4*lh;
            __builtin_nontemporal_store(vmax[r] + bv,
                out + (wbase + row)*WEDIM + colb + ln31);
        }
    }
}

extern "C" void kernel_launch(void* const* d_in, const int* in_sizes, int n_in,
                              void* d_out, int out_size, void* d_ws, size_t ws_size,
                              hipStream_t stream) {
    const float* cemb     = (const float*)d_in[0];   // char_emb_w [256*32]
    const float* cnn      = (const float*)d_in[1];   // cnn_w [512*33*4]
    const int*   data     = (const int*)d_in[2];     // [16384]
    const int*   spelling = (const int*)d_in[3];     // [50000*20]
    float* outp = (float*)d_out;

    unsigned short* wbf3   = (unsigned short*)d_ws;                       // 131072 B
    float*          bias   = (float*)((char*)d_ws + 131072);              // 2048 B
    unsigned short* cembbf = (unsigned short*)((char*)d_ws + 133120);     // 16384 B

    int prep_items = 65536 + 256*CEDIM + WEDIM;   // 74240
    prep_kernel<<<dim3((prep_items + 255)/256), dim3(256), 0, stream>>>(cnn, cemb, wbf3, cembbf, bias);
    conv_kernel<<<dim3(NBLK), dim3(512), 0, stream>>>(data, spelling, cembbf, wbf3, bias, outp);
}